// Round 1
// baseline (731.887 us; speedup 1.0000x reference)
//
#include <hip/hip_runtime.h>
#include <cstdint>
#include <cstddef>

typedef __bf16 bf16;
typedef bf16  bf16x8  __attribute__((ext_vector_type(8)));
typedef bf16  bf16x4  __attribute__((ext_vector_type(4)));
typedef float floatx4 __attribute__((ext_vector_type(4)));

#define D_MODEL 4096
#define NROWS   2048      // B*S
#define SEQ     1024
#define NHEADS  32
#define HDIM    128

// async global->LDS, 16B per lane; LDS dest is wave-uniform base (HW adds lane*16)
__device__ __forceinline__ void async16(const void* g, void* s) {
    __builtin_amdgcn_global_load_lds(
        (__attribute__((address_space(1))) void*)g,
        (__attribute__((address_space(3))) void*)s,
        16, 0, 0);
}

// ---------------- fp32 -> bf16 convert (4 elems/thread) ----------------
__global__ __launch_bounds__(256) void cvt_kernel(const float* __restrict__ in,
                                                  bf16* __restrict__ out, int n4) {
    int i = blockIdx.x * 256 + threadIdx.x;
    if (i >= n4) return;
    const float4 v = ((const float4*)in)[i];
    bf16x4 o;
    o[0] = (bf16)v.x; o[1] = (bf16)v.y; o[2] = (bf16)v.z; o[3] = (bf16)v.w;
    ((bf16x4*)out)[i] = o;
}

// ---------------- vectorized RoPE: 8 contiguous elems (4 pairs) per thread ----------------
__global__ __launch_bounds__(256) void rope_kernel(bf16* __restrict__ Qb,
                                                   bf16* __restrict__ Kb,
                                                   const float* __restrict__ fc,
                                                   const float* __restrict__ fs) {
    int t = blockIdx.x * 256 + threadIdx.x;
    const bool isK = (t >> 20) != 0;
    bf16* p = isK ? Kb : Qb;
    const float qs = isK ? 1.0f : 0.08838834764831845f;
    int i = t & 1048575;
    int e = i * 8;
    int row = e >> 12;
    int coff = e & 4095;
    int s = row & 1023;
    int d0 = (coff & 127) >> 1;

    bf16x8 v = *(bf16x8*)(p + (size_t)row * D_MODEL + coff);
    float4 c4 = *(const float4*)&fc[s * 64 + d0];
    float4 s4 = *(const float4*)&fs[s * 64 + d0];
    float cc[4] = {c4.x, c4.y, c4.z, c4.w};
    float ss[4] = {s4.x, s4.y, s4.z, s4.w};
    bf16x8 o;
#pragma unroll
    for (int j = 0; j < 4; j++) {
        float e0 = (float)v[2 * j], e1 = (float)v[2 * j + 1];
        o[2 * j]     = (bf16)((e0 * cc[j] - e1 * ss[j]) * qs);
        o[2 * j + 1] = (bf16)((e0 * ss[j] + e1 * cc[j]) * qs);
    }
    *(bf16x8*)(p + (size_t)row * D_MODEL + coff) = o;
}

// ---------------- 128x128 tile bf16 GEMM, C = A @ B^T (m97 structure) — kept for wo ----------------
template<bool F32OUT>
__global__ __launch_bounds__(256) void gemm_bt(const bf16* __restrict__ A,
                                               const bf16* __restrict__ B0,
                                               void* __restrict__ C0) {
    __shared__ __align__(16) bf16 As[128 * 32];
    __shared__ __align__(16) bf16 Bs[128 * 32];
    const int tid  = threadIdx.x;
    const int lane = tid & 63;
    const int wave = tid >> 6;
    const int col  = lane & 15;
    const int quad = lane >> 4;
    const int bm = blockIdx.x * 128;
    const int bn = blockIdx.y * 128;
    const int wm = (wave >> 1) * 64;
    const int wn = (wave & 1) * 64;
    const bf16* Bw = B0 + (size_t)blockIdx.z * ((size_t)D_MODEL * D_MODEL);

    floatx4 acc[4][4] = {};

    for (int k0 = 0; k0 < D_MODEL; k0 += 32) {
#pragma unroll
        for (int j = 0; j < 2; j++) {
            int c   = j * 256 + tid;
            int row = c >> 2;
            int kc  = (c & 3) * 8;
            void* dstA = (void*)(As + (size_t)(j * 256 + wave * 64) * 8);
            void* dstB = (void*)(Bs + (size_t)(j * 256 + wave * 64) * 8);
            async16(A  + (size_t)(bm + row) * D_MODEL + k0 + kc, dstA);
            async16(Bw + (size_t)(bn + row) * D_MODEL + k0 + kc, dstB);
        }
        __syncthreads();
        bf16x8 a[4], b[4];
#pragma unroll
        for (int i = 0; i < 4; i++)
            a[i] = *(const bf16x8*)&As[(wm + i * 16 + col) * 32 + quad * 8];
#pragma unroll
        for (int j = 0; j < 4; j++)
            b[j] = *(const bf16x8*)&Bs[(wn + j * 16 + col) * 32 + quad * 8];
#pragma unroll
        for (int i = 0; i < 4; i++)
#pragma unroll
            for (int j = 0; j < 4; j++)
                acc[i][j] = __builtin_amdgcn_mfma_f32_16x16x32_bf16(a[i], b[j], acc[i][j], 0, 0, 0);
        __syncthreads();
    }

#pragma unroll
    for (int i = 0; i < 4; i++) {
#pragma unroll
        for (int j = 0; j < 4; j++) {
            int row = bm + wm + i * 16 + quad * 4;
            int cg  = bn + wn + j * 16 + col;
#pragma unroll
            for (int r = 0; r < 4; r++) {
                if constexpr (F32OUT) {
                    ((float*)C0)[(size_t)(row + r) * D_MODEL + cg] = acc[i][j][r];
                } else {
                    bf16* C = (bf16*)C0 + (size_t)blockIdx.z * ((size_t)NROWS * D_MODEL);
                    C[(size_t)(row + r) * D_MODEL + cg] = (bf16)acc[i][j][r];
                }
            }
        }
    }
}

// ---------------- fused QKV GEMM: 256x256 tile, BK=64, 8-phase counted-vmcnt schedule ----------------
// A: [2048][4096] bf16, W: [12288][4096] bf16 (wq,wk,wv stacked), C: [3][2048][4096] bf16.
// 512 threads = 8 waves (2M x 4N); per-wave output 128x64 (acc[8][4]).
// LDS: 8 slots of 16KB: [buf][khalf][A/B], each 256 rows x 32 k (64B rows -> conflict-free b128 frag reads).
// Per tile (4 phases): (k0,mlo)+stage(t+1 A_k1) | (k0,mhi)+stage(t+2 B_k0) |
//                      (k1,mlo)+stage(t+2 A_k0) | (k1,mhi)+stage(t+2 B_k1)+vmcnt(6).
// Each phase: ds_reads; stage issue; s_barrier; setprio(1); 16 MFMA; setprio(0); [vmcnt(6)]; s_barrier.
#define QSTAGE(buf, kh, ab, base, o0, o1, koff) do {                        \
    bf16* s_ = &lds[(((buf) << 2) | ((kh) << 1) | (ab))][0];                \
    async16((base) + (o0) + (koff), s_ + ldsw0);                            \
    async16((base) + (o1) + (koff), s_ + 4096 + ldsw0);                     \
} while (0)

#define QPHASE(buf, kh, mh, STAGE_STMT, VM_STMT) do {                       \
    const bf16* sA_ = &lds[(((buf) << 2) | ((kh) << 1))][0];                \
    const bf16* sB_ = sA_ + 8192;                                           \
    bf16x8 af_[4];                                                          \
    _Pragma("unroll")                                                       \
    for (int i_ = 0; i_ < 4; ++i_) {                                        \
        int row_ = wm + ((mh) * 4 + i_) * 16 + col;                         \
        af_[i_] = *(const bf16x8*)&sA_[row_ * 32 + quad * 8];               \
    }                                                                       \
    if ((mh) == 0) {                                                        \
        _Pragma("unroll")                                                   \
        for (int n_ = 0; n_ < 4; ++n_) {                                    \
            int row_ = wn + n_ * 16 + col;                                  \
            bfr[n_] = *(const bf16x8*)&sB_[row_ * 32 + quad * 8];           \
        }                                                                   \
    }                                                                       \
    STAGE_STMT;                                                             \
    __builtin_amdgcn_s_barrier();                                           \
    __builtin_amdgcn_s_setprio(1);                                          \
    _Pragma("unroll")                                                       \
    for (int i_ = 0; i_ < 4; ++i_)                                          \
        _Pragma("unroll")                                                   \
        for (int n_ = 0; n_ < 4; ++n_)                                      \
            acc[(mh) * 4 + i_][n_] = __builtin_amdgcn_mfma_f32_16x16x32_bf16( \
                af_[i_], bfr[n_], acc[(mh) * 4 + i_][n_], 0, 0, 0);         \
    __builtin_amdgcn_s_setprio(0);                                          \
    VM_STMT;                                                                \
    __builtin_amdgcn_s_barrier();                                           \
} while (0)

__global__ __launch_bounds__(512, 2) void gemm_qkv(const bf16* __restrict__ A,
                                                   const bf16* __restrict__ W,
                                                   bf16* __restrict__ C) {
    __shared__ __align__(16) bf16 lds[8][8192];   // 128 KiB

    const int tid  = threadIdx.x;
    const int lane = tid & 63;
    const int wave = tid >> 6;
    const int col  = lane & 15;
    const int quad = lane >> 4;

    // XCD-bijective swizzle: 384 wg = 8 XCDs x (8 mt x 6 nt); each XCD keeps the
    // full A k-slice (2048x64x2B = 256KB) + its 6-nt B panel L2-resident.
    const int bid = blockIdx.x;
    const int xcd = bid & 7;
    const int li  = bid >> 3;
    const int mt  = li & 7;
    const int nt  = xcd * 6 + (li >> 3);
    const int bm  = mt << 8;
    const size_t bnr = (size_t)nt << 8;           // W row base (fused N = 12288)

    const int wm = (wave >> 2) << 7;              // 0 / 128
    const int wn = (wave & 3) << 6;               // 0 / 64 / 128 / 192

    // staging constants: chunk c = j*512+tid -> row=c>>2 (j adds 128), granule=c&3
    const int r0 = tid >> 2, g0 = tid & 3;
    const size_t offA0 = (size_t)(bm + r0) * D_MODEL + g0 * 8;
    const size_t offA1 = offA0 + (size_t)128 * D_MODEL;
    const size_t offB0 = (bnr + (size_t)r0) * D_MODEL + g0 * 8;
    const size_t offB1 = offB0 + (size_t)128 * D_MODEL;
    const int ldsw0 = wave * 512;                 // element offset of wave's dest (j=0)

    floatx4 acc[8][4] = {};
    bf16x8 bfr[4];

    // ---- prologue: tile0 (all 4 halves) + tile1 (B_k0, A_k0, B_k1) ----
    QSTAGE(0, 0, 0, A, offA0, offA1, 0);
    QSTAGE(0, 0, 1, W, offB0, offB1, 0);
    QSTAGE(0, 1, 0, A, offA0, offA1, 32);
    QSTAGE(0, 1, 1, W, offB0, offB1, 32);
    QSTAGE(1, 0, 1, W, offB0, offB1, 64);
    QSTAGE(1, 0, 0, A, offA0, offA1, 64);
    QSTAGE(1, 1, 1, W, offB0, offB1, 96);
    asm volatile("s_waitcnt vmcnt(6)" ::: "memory");   // tile0 fully landed
    __builtin_amdgcn_s_barrier();

    for (int t = 0; t < 64; ++t) {
        const int buf = t & 1;
        const int k1 = ((t + 1 < 64) ? t + 1 : 63) * 64;   // tail clamp: writes only dead slots
        const int k2 = ((t + 2 < 64) ? t + 2 : 63) * 64;
        QPHASE(buf, 0, 0, QSTAGE(buf ^ 1, 1, 0, A, offA0, offA1, k1 + 32), );
        QPHASE(buf, 0, 1, QSTAGE(buf,     0, 1, W, offB0, offB1, k2), );
        QPHASE(buf, 1, 0, QSTAGE(buf,     0, 0, A, offA0, offA1, k2), );
        QPHASE(buf, 1, 1, QSTAGE(buf,     1, 1, W, offB0, offB1, k2 + 32),
               asm volatile("s_waitcnt vmcnt(6)" ::: "memory"));
    }
    asm volatile("s_waitcnt vmcnt(0)" ::: "memory");   // drain before epilogue/end

    // ---- epilogue: C[z][row][col], z = nt/16 ----
    const size_t zb = (size_t)(nt >> 4) * ((size_t)NROWS * D_MODEL);
    const int bn = (nt & 15) << 8;
#pragma unroll
    for (int m = 0; m < 8; ++m) {
#pragma unroll
        for (int n = 0; n < 4; ++n) {
            const int row = bm + wm + m * 16 + quad * 4;
            const int cg  = bn + wn + n * 16 + col;
#pragma unroll
            for (int r = 0; r < 4; ++r)
                C[zb + (size_t)(row + r) * D_MODEL + cg] = (bf16)acc[m][n][r];
        }
    }
}

// ---------------- flash attention: 128q block (4 waves x 32q), 64-key tiles ----------------
#define PST 72   // Ps row stride (elements)

__global__ __launch_bounds__(256, 2) void attn_kernel(const bf16* __restrict__ Qb,
                                                      const bf16* __restrict__ Kb,
                                                      const bf16* __restrict__ Vb,
                                                      bf16* __restrict__ Ob) {
    __shared__ __align__(16) bf16 Ks[64 * 128];
    __shared__ __align__(16) bf16 Vt[128 * 64];
    __shared__ __align__(16) bf16 Ps[4 * 32 * PST];

    const int tid  = threadIdx.x;
    const int lane = tid & 63;
    const int wave = tid >> 6;
    const int col  = lane & 15;
    const int quad = lane >> 4;
    const int hb   = tid & 15;
    const int kb   = tid >> 4;

    const int b   = blockIdx.z;
    const int h   = blockIdx.y;
    const int ex  = b ? (7 - blockIdx.x) : blockIdx.x;
    const int q0b = ex * 128;
    const int q0w = q0b + wave * 32;
    const size_t bh = (size_t)(b * SEQ) * D_MODEL + h * HDIM;

    bf16x8 qf[2][4];
#pragma unroll
    for (int qi = 0; qi < 2; qi++)
#pragma unroll
        for (int kc = 0; kc < 4; kc++)
            qf[qi][kc] = *(const bf16x8*)(Qb + bh + (size_t)(q0w + qi * 16 + col) * D_MODEL + kc * 32 + quad * 8);

    floatx4 o[2][8];
    floatx4 ol[2];
#pragma unroll
    for (int qi = 0; qi < 2; qi++) {
        ol[qi] = (floatx4){0.f, 0.f, 0.f, 0.f};
#pragma unroll
        for (int c = 0; c < 8; c++) o[qi][c] = (floatx4){0.f, 0.f, 0.f, 0.f};
    }

    bf16x8 ones;
#pragma unroll
    for (int t = 0; t < 8; t++) ones[t] = (bf16)1.0f;

    bf16* Psw = Ps + wave * 32 * PST;
    const int nkt = ex * 2 + 2;

    for (int kt = 0; kt < nkt; kt++) {
        const int key0 = kt * 64;
#pragma unroll
        for (int it = 0; it < 4; it++) {
            int l = it * 256 + tid;
            int row = l >> 4, p = l & 15;
            int g = (p & 8) | ((p ^ (row & 7) ^ ((row >> 3) & 7)) & 7);
            async16(Kb + bh + (size_t)(key0 + row) * D_MODEL + g * 8,
                    (void*)(Ks + (size_t)(it * 256 + wave * 64) * 8));
        }
        {
            uint32_t uv[4][4];
#pragma unroll
            for (int i = 0; i < 4; i++) {
                uint4 t = *(const uint4*)(Vb + bh + (size_t)(key0 + kb * 4 + i) * D_MODEL + hb * 8);
                uv[i][0] = t.x; uv[i][1] = t.y; uv[i][2] = t.z; uv[i][3] = t.w;
            }
#pragma unroll
            for (int j = 0; j < 8; j++) {
                uint32_t sel = (j & 1) ? 0x07060302u : 0x05040100u;
                uint32_t w0 = __builtin_amdgcn_perm(uv[1][j >> 1], uv[0][j >> 1], sel);
                uint32_t w1 = __builtin_amdgcn_perm(uv[3][j >> 1], uv[2][j >> 1], sel);
                int row = hb * 8 + j;
                int p = ((kb >> 1) ^ (row & 7) ^ ((row >> 3) & 7)) & 7;
                uint2* dst = (uint2*)&Vt[row * 64 + p * 8 + (kb & 1) * 4];
                *dst = (uint2){w0, w1};
            }
        }
        __syncthreads();

        if (key0 <= q0w + 31) {
            const bool masked = (key0 + 63 > q0w);
            floatx4 sf[2][4];
#pragma unroll
            for (int qi = 0; qi < 2; qi++)
#pragma unroll
                for (int f = 0; f < 4; f++) sf[qi][f] = (floatx4){0.f, 0.f, 0.f, 0.f};
#pragma unroll
            for (int kc = 0; kc < 4; kc++)
#pragma unroll
                for (int f = 0; f < 4; f++) {
                    int row = f * 16 + col;
                    int g = kc * 4 + quad;
                    int p = (g & 8) | ((g ^ (row & 7) ^ ((row >> 3) & 7)) & 7);
                    bf16x8 kf = *(const bf16x8*)&Ks[row * 128 + p * 8];
                    sf[0][f] = __builtin_amdgcn_mfma_f32_16x16x32_bf16(qf[0][kc], kf, sf[0][f], 0, 0, 0);
                    sf[1][f] = __builtin_amdgcn_mfma_f32_16x16x32_bf16(qf[1][kc], kf, sf[1][f], 0, 0, 0);
                }
#pragma unroll
            for (int qi = 0; qi < 2; qi++)
#pragma unroll
                for (int f = 0; f < 4; f++) {
                    int key = key0 + f * 16 + col;
#pragma unroll
                    for (int r = 0; r < 4; r++) {
                        float pv;
                        if (masked)
                            pv = (key <= q0w + qi * 16 + quad * 4 + r) ? __expf(sf[qi][f][r]) : 0.f;
                        else
                            pv = __expf(sf[qi][f][r]);
                        Psw[(qi * 16 + quad * 4 + r) * PST + f * 16 + col] = (bf16)pv;
                    }
                }
#pragma unroll
            for (int kc = 0; kc < 2; kc++) {
                bf16x8 pa0 = *(const bf16x8*)&Psw[(0 * 16 + col) * PST + kc * 32 + quad * 8];
                bf16x8 pa1 = *(const bf16x8*)&Psw[(1 * 16 + col) * PST + kc * 32 + quad * 8];
                ol[0] = __builtin_amdgcn_mfma_f32_16x16x32_bf16(pa0, ones, ol[0], 0, 0, 0);
                ol[1] = __builtin_amdgcn_mfma_f32_16x16x32_bf16(pa1, ones, ol[1], 0, 0, 0);
#pragma unroll
                for (int c = 0; c < 8; c++) {
                    int row = c * 16 + col;
                    int g = kc * 4 + quad;
                    int p = (g ^ (row & 7) ^ ((row >> 3) & 7)) & 7;
                    bf16x8 vf = *(const bf16x8*)&Vt[row * 64 + p * 8];
                    o[0][c] = __builtin_amdgcn_mfma_f32_16x16x32_bf16(pa0, vf, o[0][c], 0, 0, 0);
                    o[1][c] = __builtin_amdgcn_mfma_f32_16x16x32_bf16(pa1, vf, o[1][c], 0, 0, 0);
                }
            }
        }
        __syncthreads();
    }

#pragma unroll
    for (int qi = 0; qi < 2; qi++) {
        float inv[4];
#pragma unroll
        for (int r = 0; r < 4; r++) inv[r] = 1.0f / ol[qi][r];
#pragma unroll
        for (int c = 0; c < 8; c++)
#pragma unroll
            for (int r = 0; r < 4; r++)
                Ob[bh + (size_t)(q0w + qi * 16 + quad * 4 + r) * D_MODEL + c * 16 + col] =
                    (bf16)(o[qi][c][r] * inv[r]);
    }
}

// ---------------- launch ----------------
extern "C" void kernel_launch(void* const* d_in, const int* in_sizes, int n_in,
                              void* d_out, int out_size, void* d_ws, size_t ws_size,
                              hipStream_t stream) {
    const float* x  = (const float*)d_in[0];
    const float* fc = (const float*)d_in[1];
    const float* fs = (const float*)d_in[2];
    const float* wq = (const float*)d_in[6];
    const float* wk = (const float*)d_in[7];
    const float* wv = (const float*)d_in[8];
    const float* wo = (const float*)d_in[9];

    char* ws    = (char*)d_ws;
    bf16* xb    = (bf16*)(ws);                               // 2048x4096
    bf16* wb    = (bf16*)(ws + 16777216ull);                 // 3 x 4096x4096 (wo reuses slot 0 later)
    bf16* qkvb  = (bf16*)(ws + 117440512ull);                // 3 x 2048x4096 (Q,K,V)
    bf16* attnb = (bf16*)(ws + 167772160ull);                // 2048x4096

    // fp32 -> bf16
    cvt_kernel<<<8192,  256, 0, stream>>>(x,  xb,                   2097152);
    cvt_kernel<<<16384, 256, 0, stream>>>(wq, wb + 0ull * 16777216, 4194304);
    cvt_kernel<<<16384, 256, 0, stream>>>(wk, wb + 1ull * 16777216, 4194304);
    cvt_kernel<<<16384, 256, 0, stream>>>(wv, wb + 2ull * 16777216, 4194304);

    // fused QKV projection: [2048,4096] @ [12288,4096]^T, 256^2 8-phase schedule
    gemm_qkv<<<dim3(384), 512, 0, stream>>>(xb, wb, qkvb);

    // wo -> bf16 into wq's slot (wq dead now)
    cvt_kernel<<<16384, 256, 0, stream>>>(wo, wb, 4194304);

    // RoPE (+ Q scale) in-place, vectorized
    rope_kernel<<<8192, 256, 0, stream>>>(qkvb, qkvb + 8388608ull, fc, fs);

    // attention
    attn_kernel<<<dim3(8, 32, 2), 256, 0, stream>>>(qkvb, qkvb + 8388608ull,
                                                    qkvb + 16777216ull, attnb);

    // output projection (fp32 out)
    gemm_bt<true><<<dim3(16, 32, 1), 256, 0, stream>>>(attnb, wb, d_out);
}